// Round 7
// baseline (811.709 us; speedup 1.0000x reference)
//
#include <hip/hip_runtime.h>
#include <cstddef>
#include <cstdint>

#define CDIV(a,b) (((a)+(b)-1)/(b))
#define NEG_SLOPE 0.2f

typedef unsigned short u16;
typedef __attribute__((ext_vector_type(8))) short bf16x8;
typedef __attribute__((ext_vector_type(4))) float f32x4;

// ---------- bf16 helpers (explicit RNE, hi/lo split: v ~= hi + lo, ~17 mantissa bits) ----------
__device__ __forceinline__ u16 bf16_rne(float v){
  unsigned u = __float_as_uint(v);
  unsigned r = (u + 0x7FFFu + ((u >> 16) & 1u)) >> 16;
  return (u16)r;
}
__device__ __forceinline__ float bf16_to_f(u16 h){
  return __uint_as_float(((unsigned)h) << 16);
}
__device__ __forceinline__ void f2hilo(float v, u16& h, u16& l){
  h = bf16_rne(v);
  float r = v - bf16_to_f(h);
  l = bf16_rne(r);
}

// ---------- monotonic float<->uint encoding for atomicMax on floats ----------
__device__ __forceinline__ unsigned enc_f(float x){
  unsigned u = __float_as_uint(x);
  return (u & 0x80000000u) ? ~u : (u | 0x80000000u);
}
__device__ __forceinline__ float dec_f(unsigned k){
  unsigned u = (k & 0x80000000u) ? (k & 0x7FFFFFFFu) : ~k;
  return __uint_as_float(u);
}

__device__ __forceinline__ float sigmf(float x){ return 1.f / (1.f + expf(-x)); }

// ---------- async global->LDS, 16B per lane ----------
__device__ __forceinline__ void gload16(const void* g, void* l){
  __builtin_amdgcn_global_load_lds((const __attribute__((address_space(1))) void*)g,
                                   (__attribute__((address_space(3))) void*)l, 16, 0, 0);
}

// =====================================================================================
// BIG-TILE fused hi/lo MFMA GEMM: 256x256 tile, 512 thr (8 waves, 2Mx4N), BK=32,
// double-buffered LDS (2 buf x 4 tiles x [256][32] bf16 = 128KB), counted vmcnt (T4).
//   C[M,N] = sum_pairs (A_hi+A_lo)(B_hi+B_lo)^T, dropping lo*lo.
// Per K-tile: per-wave 96 MFMA -> per-SIMD compute window ~930cyc >= HBM latency (~900)
// so the depth-2 prefetch actually covers it (round-6's 128-tile window was only ~470).
// BN=256 -> A fetched once for N=256 GEMMs (FETCH halves vs round 6).
// Swizzle (round-6 verified, 0 conflicts): LDS (row, phys-slot) holds global slot
// (phys-(row>>1))&3 via pre-swizzled global source; reader uses phys=(lq+(r>>1))&3.
// B stored transposed [N][K] bf16. N%256==0, K%32==0, M arbitrary.
// Epilogues: (a) f32 C (+bias), (b) hi/lo bf16, (c) fused LSTM (gate-interleaved B).
// =====================================================================================
__global__ __launch_bounds__(512, 2) void mfma_gemm256(
    const u16* __restrict__ Ah0, const u16* __restrict__ Al0,
    const u16* __restrict__ Bh0, const u16* __restrict__ Bl0,
    const u16* __restrict__ Ah1, const u16* __restrict__ Al1,
    const u16* __restrict__ Bh1, const u16* __restrict__ Bl1,
    int npairs, int M, int N, int K,
    const float* __restrict__ bias, float* __restrict__ Cf,
    u16* __restrict__ outHi, u16* __restrict__ outLo,
    const float* __restrict__ cIn, float* __restrict__ cOut,
    u16* __restrict__ hH, u16* __restrict__ hL, int lstm_first)
{
  // u16 units: buffer stride 32768 (64KB); tiles Ah@0 Al@8192 Bh@16384 Bl@24576
  __shared__ u16 smem[2 * 32768];
  const int tid = threadIdx.x;
  const int lane = tid & 63, wv = tid >> 6;
  const int l15 = lane & 15, lq = lane >> 4;
  const int wr = wv >> 2, wc = wv & 3;          // 2 x 4 wave grid; wave tile 128x64
  const int bm = blockIdx.y * 256, bn = blockIdx.x * 256;
  const int rmA = M - bm;  // >= 1
  const int KT = K >> 5, NT = npairs * KT;

  f32x4 acc[8][4];
  #pragma unroll
  for (int m = 0; m < 8; m++)
    #pragma unroll
    for (int n = 0; n < 4; n++) acc[m][n] = (f32x4){0.f, 0.f, 0.f, 0.f};

  // staging geometry: tile = 1024 chunks of 16B; chunk c = i*512+tid; row=c>>2,
  // phys slot=c&3, logical slot s=(phys-(row>>1))&3 (inverse-swizzled global source)
  size_t gaoff[2], gboff[2]; int ldso2[2];
  #pragma unroll
  for (int i = 0; i < 2; i++){
    int c = i * 512 + tid;
    int row = c >> 2, phys = c & 3;
    int s = (phys - (row >> 1)) & 3;
    int rowA = row < rmA ? row : rmA - 1;          // clamp A tail rows
    gaoff[i] = (size_t)(bm + rowA) * K + s * 8;
    gboff[i] = (size_t)(bn + row) * K + s * 8;
    ldso2[i] = (i * 512 + (tid & 448)) * 8;        // wave-uniform base, u16 units
  }

  // fragment read offsets (u16 units within a buffer); phys slot = (lq + (r>>1)) & 3
  int aoff[8], boff[4];
  #pragma unroll
  for (int m = 0; m < 8; m++){
    int r = wr * 128 + m * 16 + l15;
    aoff[m] = r * 32 + ((lq + (r >> 1)) & 3) * 8;
  }
  #pragma unroll
  for (int n = 0; n < 4; n++){
    int r = wc * 64 + n * 16 + l15;
    boff[n] = r * 32 + ((lq + (r >> 1)) & 3) * 8;
  }

  auto stage = [&](int buf, int t){
    int q = (npairs > 1 && t >= KT) ? 1 : 0;
    const u16* A_h = q ? Ah1 : Ah0;  const u16* A_l = q ? Al1 : Al0;
    const u16* B_h = q ? Bh1 : Bh0;  const u16* B_l = q ? Bl1 : Bl0;
    int k0 = (q ? t - KT : t) << 5;
    u16* sb = smem + buf * 32768;
    #pragma unroll
    for (int i = 0; i < 2; i++){
      gload16(A_h + gaoff[i] + k0, sb + ldso2[i]);
      gload16(A_l + gaoff[i] + k0, sb + 8192 + ldso2[i]);
      gload16(B_h + gboff[i] + k0, sb + 16384 + ldso2[i]);
      gload16(B_l + gboff[i] + k0, sb + 24576 + ldso2[i]);
    }
  };

  stage(0, 0);                  // 8 loads/wave outstanding
  int cur = 0;
  #pragma unroll 1
  for (int t = 0; t < NT; t++){
    if (t + 1 < NT){
      stage(cur ^ 1, t + 1);    // +8 -> up to 16 outstanding
      asm volatile("s_waitcnt vmcnt(8)" ::: "memory");   // tile-t landed; t+1 in flight
    } else {
      asm volatile("s_waitcnt vmcnt(0)" ::: "memory");
    }
    __builtin_amdgcn_sched_barrier(0);
    __builtin_amdgcn_s_barrier();        // all waves' tile-t data visible in LDS
    __builtin_amdgcn_sched_barrier(0);
    const u16* sb = smem + cur * 32768;
    bf16x8 bh[4], bl[4];
    #pragma unroll
    for (int n = 0; n < 4; n++){
      bh[n] = *(const bf16x8*)(sb + 16384 + boff[n]);
      bl[n] = *(const bf16x8*)(sb + 24576 + boff[n]);
    }
    #pragma unroll
    for (int g = 0; g < 2; g++){         // 2 m-groups of 4 -> caps live A frags
      bf16x8 ah[4], al[4];
      #pragma unroll
      for (int mm = 0; mm < 4; mm++){
        ah[mm] = *(const bf16x8*)(sb + aoff[g * 4 + mm]);
        al[mm] = *(const bf16x8*)(sb + 8192 + aoff[g * 4 + mm]);
      }
      __builtin_amdgcn_s_setprio(1);
      #pragma unroll
      for (int mm = 0; mm < 4; mm++)
        #pragma unroll
        for (int n = 0; n < 4; n++){
          acc[g*4+mm][n] = __builtin_amdgcn_mfma_f32_16x16x32_bf16(ah[mm], bh[n], acc[g*4+mm][n], 0, 0, 0);
          acc[g*4+mm][n] = __builtin_amdgcn_mfma_f32_16x16x32_bf16(al[mm], bh[n], acc[g*4+mm][n], 0, 0, 0);
          acc[g*4+mm][n] = __builtin_amdgcn_mfma_f32_16x16x32_bf16(ah[mm], bl[n], acc[g*4+mm][n], 0, 0, 0);
        }
      __builtin_amdgcn_s_setprio(0);
    }
    __builtin_amdgcn_sched_barrier(0);
    __builtin_amdgcn_s_barrier();        // all waves done reading buf[cur]; NO vmcnt drain
    cur ^= 1;
  }

  // epilogue: C/D layout col=lane&15, row=(lane>>4)*4+j (m89/m91-verified)
  const int rb = bm + wr * 128 + lq * 4;
  if (cOut){
    // LSTM mode: lane owns channel ch; n-frag index == gate (i,f,g,o)
    const int ch = (bn >> 2) + wc * 16 + l15;
    #pragma unroll
    for (int m = 0; m < 8; m++){
      #pragma unroll
      for (int j = 0; j < 4; j++){
        int row = rb + m * 16 + j;
        if (row >= M) continue;
        float i_ = acc[m][0][j], f_ = acc[m][1][j], g_ = acc[m][2][j], o_ = acc[m][3][j];
        float si = sigmf(i_), tg = tanhf(g_), so = sigmf(o_);
        size_t off = (size_t)row * 256 + ch;
        float cn = lstm_first ? si * tg : sigmf(f_) * cIn[off] + si * tg;
        float hn = so * tanhf(cn);
        cOut[off] = cn;
        u16 hh, hl; f2hilo(hn, hh, hl);
        hH[off] = hh; hL[off] = hl;
      }
    }
  } else {
    const int cb = bn + wc * 64 + l15;
    #pragma unroll
    for (int n = 0; n < 4; n++){
      int col = cb + n * 16;
      float bv = bias ? bias[col] : 0.f;
      #pragma unroll
      for (int m = 0; m < 8; m++){
        #pragma unroll
        for (int j = 0; j < 4; j++){
          int row = rb + m * 16 + j;
          if (row >= M) continue;
          float v = acc[m][n][j] + bv;
          size_t off = (size_t)row * N + col;
          if (Cf) Cf[off] = v;
          if (outHi){
            u16 hh, hl; f2hilo(v, hh, hl);
            outHi[off] = hh; outLo[off] = hl;
          }
        }
      }
    }
  }
}

// =====================================================================================
// 128x128-tile variant (round-6, kept for N=128 output projection only)
// =====================================================================================
__global__ __launch_bounds__(256, 2) void mfma_gemm(
    const u16* __restrict__ Ah0, const u16* __restrict__ Al0,
    const u16* __restrict__ Bh0, const u16* __restrict__ Bl0,
    int M, int N, int K,
    const float* __restrict__ bias, float* __restrict__ Cf)
{
  __shared__ u16 smem[2 * 16384];
  const int tid = threadIdx.x;
  const int lane = tid & 63, wv = tid >> 6;
  const int l15 = lane & 15, lq = lane >> 4;
  const int wr = wv >> 1, wc = wv & 1;
  const int bm = blockIdx.y * 128, bn = blockIdx.x * 128;
  const int rmA = M - bm;
  const int NT = K >> 5;

  f32x4 acc[4][4];
  #pragma unroll
  for (int m = 0; m < 4; m++)
    #pragma unroll
    for (int n = 0; n < 4; n++) acc[m][n] = (f32x4){0.f, 0.f, 0.f, 0.f};

  size_t gaoff[2], gboff[2]; int ldso2[2];
  #pragma unroll
  for (int i = 0; i < 2; i++){
    int c = i * 256 + tid;
    int row = c >> 2, phys = c & 3;
    int s = (phys - (row >> 1)) & 3;
    int rowA = row < rmA ? row : rmA - 1;
    gaoff[i] = (size_t)(bm + rowA) * K + s * 8;
    gboff[i] = (size_t)(bn + row) * K + s * 8;
    ldso2[i] = (i * 256 + (tid & 192)) * 8;
  }
  int aoff[4], boff[4];
  #pragma unroll
  for (int m = 0; m < 4; m++){
    int r = wr * 64 + m * 16 + l15;
    aoff[m] = r * 32 + ((lq + (r >> 1)) & 3) * 8;
  }
  #pragma unroll
  for (int n = 0; n < 4; n++){
    int r = wc * 64 + n * 16 + l15;
    boff[n] = r * 32 + ((lq + (r >> 1)) & 3) * 8;
  }
  auto stage = [&](int buf, int t){
    int k0 = t << 5;
    u16* sb = smem + buf * 16384;
    #pragma unroll
    for (int i = 0; i < 2; i++){
      gload16(Ah0 + gaoff[i] + k0, sb + ldso2[i]);
      gload16(Al0 + gaoff[i] + k0, sb + 4096 + ldso2[i]);
      gload16(Bh0 + gboff[i] + k0, sb + 8192 + ldso2[i]);
      gload16(Bl0 + gboff[i] + k0, sb + 12288 + ldso2[i]);
    }
  };
  stage(0, 0);
  int cur = 0;
  #pragma unroll 1
  for (int t = 0; t < NT; t++){
    if (t + 1 < NT){
      stage(cur ^ 1, t + 1);
      asm volatile("s_waitcnt vmcnt(8)" ::: "memory");
    } else {
      asm volatile("s_waitcnt vmcnt(0)" ::: "memory");
    }
    __builtin_amdgcn_sched_barrier(0);
    __builtin_amdgcn_s_barrier();
    __builtin_amdgcn_sched_barrier(0);
    const u16* sb = smem + cur * 16384;
    bf16x8 ah[4], al[4], bh[4], bl[4];
    #pragma unroll
    for (int m = 0; m < 4; m++){
      ah[m] = *(const bf16x8*)(sb + aoff[m]);
      al[m] = *(const bf16x8*)(sb + 4096 + aoff[m]);
    }
    #pragma unroll
    for (int n = 0; n < 4; n++){
      bh[n] = *(const bf16x8*)(sb + 8192 + boff[n]);
      bl[n] = *(const bf16x8*)(sb + 12288 + boff[n]);
    }
    #pragma unroll
    for (int m = 0; m < 4; m++)
      #pragma unroll
      for (int n = 0; n < 4; n++){
        acc[m][n] = __builtin_amdgcn_mfma_f32_16x16x32_bf16(ah[m], bh[n], acc[m][n], 0, 0, 0);
        acc[m][n] = __builtin_amdgcn_mfma_f32_16x16x32_bf16(al[m], bh[n], acc[m][n], 0, 0, 0);
        acc[m][n] = __builtin_amdgcn_mfma_f32_16x16x32_bf16(ah[m], bl[n], acc[m][n], 0, 0, 0);
      }
    __builtin_amdgcn_sched_barrier(0);
    __builtin_amdgcn_s_barrier();
    cur ^= 1;
  }
  const int rb = bm + wr * 64 + lq * 4;
  const int cb = bn + wc * 64 + l15;
  #pragma unroll
  for (int n = 0; n < 4; n++){
    int col = cb + n * 16;
    float bv = bias ? bias[col] : 0.f;
    #pragma unroll
    for (int m = 0; m < 4; m++){
      #pragma unroll
      for (int j = 0; j < 4; j++){
        int row = rb + m * 16 + j;
        if (row >= M) continue;
        Cf[(size_t)row * N + col] = acc[m][n][j] + bv;
      }
    }
  }
}

// ---------- feats f32 -> hi/lo bf16, 4 elems/thread ----------
__global__ __launch_bounds__(256) void cvt_feats(const float* __restrict__ in,
    u16* __restrict__ hi, u16* __restrict__ lo, int n4){
  int i = blockIdx.x * 256 + threadIdx.x;
  if (i >= n4) return;
  float4 v = *(const float4*)(in + (size_t)i * 4);
  ushort4 h4, l4;
  f2hilo(v.x, h4.x, l4.x); f2hilo(v.y, h4.y, l4.y);
  f2hilo(v.z, h4.z, l4.z); f2hilo(v.w, h4.w, l4.w);
  *(ushort4*)(hi + (size_t)i * 4) = h4;
  *(ushort4*)(lo + (size_t)i * 4) = l4;
}

// ---------- one-shot weight prep: transpose/permute + hi/lo bf16 [N][K] ----------
// W_ih/W_hh rows are PERMUTED to gate-interleaved layout: orig row (gate*256+ch)
// -> n' = (ch>>4)*64 + gate*16 + (ch&15), so the GEMM epilogue can fuse LSTM.
__global__ __launch_bounds__(256) void prep_w(const float* __restrict__ Win,
    const float* __restrict__ Wsrc, const float* __restrict__ Wih,
    const float* __restrict__ Whh, const float* __restrict__ Wout,
    u16* WinH, u16* WinL, u16* WsH, u16* WsL,
    u16* IhH, u16* IhL, u16* HhH, u16* HhL, u16* WoH, u16* WoL){
  int idx = blockIdx.x * 256 + threadIdx.x;
  float v; u16 *ph, *pl; int off;
  if (idx < 32768){                       // WinT [256][128] <- Win[128][256]
    int n = idx >> 7, k = idx & 127;
    v = Win[k * 256 + n]; ph = WinH; pl = WinL; off = idx;
  } else if (idx < 229376){               // WsrcT [3][256][256] <- Wsrc (transposed)
    int t = idx - 32768; int hop = t >> 16, r = t & 65535, n = r >> 8, k = r & 255;
    v = Wsrc[hop * 65536 + k * 256 + n]; ph = WsH; pl = WsL; off = t;
  } else if (idx < 1015808){              // W_ih [3][1024][256], gate-interleaved rows
    int t = idx - 229376;
    int hop = t >> 18, r = (t >> 8) & 1023, k = t & 255;
    int gate = r >> 8, ch = r & 255;
    int np = ((ch >> 4) << 6) + (gate << 4) + (ch & 15);
    v = Wih[t]; ph = IhH; pl = IhL; off = hop * 262144 + np * 256 + k;
  } else if (idx < 1802240){              // W_hh, same permutation
    int t = idx - 1015808;
    int hop = t >> 18, r = (t >> 8) & 1023, k = t & 255;
    int gate = r >> 8, ch = r & 255;
    int np = ((ch >> 4) << 6) + (gate << 4) + (ch & 15);
    v = Whh[t]; ph = HhH; pl = HhL; off = hop * 262144 + np * 256 + k;
  } else if (idx < 1835008){              // WoutT [128][256] <- Wout[256][128]
    int t = idx - 1802240; int n = t >> 8, k = t & 255;
    v = Wout[k * 128 + n]; ph = WoH; pl = WoL; off = t;
  } else return;
  u16 hh, hl; f2hilo(v, hh, hl);
  ph[off] = hh; pl[off] = hl;
}

// ---------- w_s[hop] = Wsrc[hop]@a_s, w_d[hop] = Wdst[hop]@a_d (row dots, f32) ----------
__global__ __launch_bounds__(256) void prep_wvec(const float* __restrict__ Wsrc,
    const float* __restrict__ Wdst, const float* __restrict__ as_,
    const float* __restrict__ ad_, float* __restrict__ wsv, float* __restrict__ wdv){
  int wid = blockIdx.x * 4 + (threadIdx.x >> 6), lane = threadIdx.x & 63;
  if (wid >= 6 * 256) return;
  int vec = wid >> 8, i = wid & 255;
  int hop = vec >> 1; bool isd = vec & 1;
  const float* Wrow = (isd ? Wdst : Wsrc) + (size_t)hop * 65536 + (size_t)i * 256;
  const float* a = (isd ? ad_ : as_) + hop * 256;
  float4 w4 = *(const float4*)(Wrow + lane * 4);
  float4 a4 = *(const float4*)(a + lane * 4);
  float v = w4.x * a4.x + w4.y * a4.y + w4.z * a4.z + w4.w * a4.w;
  #pragma unroll
  for (int off = 32; off; off >>= 1) v += __shfl_down(v, off);
  if (!lane) (isd ? wdv : wsv)[hop * 256 + i] = v;
}

// ---------- alpha_s[m]=x[m]@w_s, alpha_d[m]=x[m]@w_d from hi/lo x; one wave/row ----------
__global__ __launch_bounds__(256) void alpha_mv(const u16* __restrict__ xh,
    const u16* __restrict__ xl, const float* __restrict__ wsv, const float* __restrict__ wdv,
    float* __restrict__ as_out, float* __restrict__ ad_out, int ns, int nd){
  int wid = blockIdx.x * 4 + (threadIdx.x >> 6), lane = threadIdx.x & 63;
  if (wid >= ns + nd) return;
  bool isd = wid >= ns;
  int row = isd ? wid - ns : wid;
  ushort4 vh = *(const ushort4*)(xh + (size_t)row * 256 + lane * 4);
  ushort4 vl = *(const ushort4*)(xl + (size_t)row * 256 + lane * 4);
  const float* wv = isd ? wdv : wsv;
  float4 w4 = *(const float4*)(wv + lane * 4);
  float v = (bf16_to_f(vh.x) + bf16_to_f(vl.x)) * w4.x
          + (bf16_to_f(vh.y) + bf16_to_f(vl.y)) * w4.y
          + (bf16_to_f(vh.z) + bf16_to_f(vl.z)) * w4.z
          + (bf16_to_f(vh.w) + bf16_to_f(vl.w)) * w4.w;
  #pragma unroll
  for (int off = 32; off; off >>= 1) v += __shfl_down(v, off);
  if (!lane) (isd ? ad_out : as_out)[row] = v;
}

// ---------- edges + self-loops: leaky-relu alpha, segment max (encoded), degree ----------
__global__ __launch_bounds__(256) void edge_a(const int* __restrict__ src,
    const int* __restrict__ dst, const float* __restrict__ as_, const float* __restrict__ ad_,
    float* __restrict__ alpha_e, float* __restrict__ alpha_self,
    unsigned* __restrict__ amax, int* __restrict__ cnt, int E, int nd){
  int i = blockIdx.x * 256 + threadIdx.x;
  if (i < E){
    int s = src[i], d = dst[i];
    float al = as_[s] + ad_[d];
    al = al > 0.f ? al : NEG_SLOPE * al;
    alpha_e[i] = al;
    atomicMax(&amax[d], enc_f(al));
    atomicAdd(&cnt[d], 1);
  } else if (i < E + nd){
    int j = i - E;
    float al = as_[j] + ad_[j];
    al = al > 0.f ? al : NEG_SLOPE * al;
    alpha_self[j] = al;
    atomicMax(&amax[j], enc_f(al));
  }
}

// ---------- scan, 2 dispatches: per-block totals, then finalize ----------
__global__ __launch_bounds__(256) void scan_part(const int* __restrict__ cnt,
    int* __restrict__ part, int n){
  __shared__ int ws_[4];
  int lane = threadIdx.x & 63, wv = threadIdx.x >> 6;
  int i = blockIdx.x * 256 + threadIdx.x;
  int v = (i < n) ? cnt[i] : 0;
  #pragma unroll
  for (int off = 32; off; off >>= 1) v += __shfl_down(v, off);
  if (!lane) ws_[wv] = v;
  __syncthreads();
  if (!threadIdx.x) part[blockIdx.x] = ws_[0] + ws_[1] + ws_[2] + ws_[3];
}
__global__ __launch_bounds__(256) void scan_fin(const int* __restrict__ cnt,
    const int* __restrict__ part, int* __restrict__ base, int* __restrict__ cursor,
    int n, int nb){
  __shared__ int ps[128];
  __shared__ int wtot[4];
  int t = threadIdx.x;
  if (t < 128) ps[t] = (t < nb) ? part[t] : 0;
  __syncthreads();
  #pragma unroll
  for (int off = 1; off < 128; off <<= 1){
    int v = (t < 128 && t >= off) ? ps[t - off] : 0;
    __syncthreads();
    if (t < 128) ps[t] += v;
    __syncthreads();
  }
  int lane = t & 63, wv = t >> 6;
  int i = blockIdx.x * 256 + t;
  int v = (i < n) ? cnt[i] : 0;
  int incl = v;
  #pragma unroll
  for (int off = 1; off < 64; off <<= 1){
    int s = __shfl_up(incl, off);
    if (lane >= off) incl += s;
  }
  if (lane == 63) wtot[wv] = incl;
  __syncthreads();
  int woff = blockIdx.x ? ps[blockIdx.x - 1] : 0;
  for (int w = 0; w < wv; w++) woff += wtot[w];
  int excl = woff + incl - v;
  if (i < n){ base[i] = excl; cursor[i] = excl; }
}

// ---------- e=exp(alpha-amax), CSR fill ----------
__global__ __launch_bounds__(256) void edge_b(const int* __restrict__ src,
    const int* __restrict__ dst, const float* __restrict__ alpha_e,
    const unsigned* __restrict__ amax, int* __restrict__ cursor,
    int* __restrict__ csr_src, float* __restrict__ csr_e, int E){
  int e = blockIdx.x * 256 + threadIdx.x;
  if (e >= E) return;
  int d = dst[e];
  float ev = expf(alpha_e[e] - dec_f(amax[d]));
  int pos = atomicAdd(&cursor[d], 1);
  csr_src[pos] = src[e];
  csr_e[pos] = ev;
}

// ---------- gather + normalize + bias + tanh -> xb hi/lo bf16; one wave/dst ----------
__global__ __launch_bounds__(256) void gather_xb(const float* __restrict__ xs,
    const int* __restrict__ base, const int* __restrict__ cnt,
    const int* __restrict__ csr_src, const float* __restrict__ csr_e,
    const float* __restrict__ alpha_self, const unsigned* __restrict__ amax,
    const float* __restrict__ gb, u16* __restrict__ xbH, u16* __restrict__ xbL, int n){
  int wv = threadIdx.x >> 6, lane = threadIdx.x & 63;
  int j = blockIdx.x * 4 + wv;
  if (j >= n) return;
  int b0 = base[j], cn = cnt[j];
  float ax = 0.f, ay = 0.f, az = 0.f, aw = 0.f, ds = 0.f;
  for (int k = 0; k < cn; k++){
    int s = csr_src[b0 + k];
    float ev = csr_e[b0 + k];
    float4 x4 = *(const float4*)(xs + (size_t)s * 256 + lane * 4);
    ax += ev * x4.x; ay += ev * x4.y; az += ev * x4.z; aw += ev * x4.w; ds += ev;
  }
  float es = expf(alpha_self[j] - dec_f(amax[j]));
  float4 x4 = *(const float4*)(xs + (size_t)j * 256 + lane * 4);
  ax += es * x4.x; ay += es * x4.y; az += es * x4.z; aw += es * x4.w; ds += es;
  float inv = 1.f / ds;
  float4 g4 = *(const float4*)(gb + lane * 4);
  float o0 = tanhf(ax * inv + g4.x), o1 = tanhf(ay * inv + g4.y);
  float o2 = tanhf(az * inv + g4.z), o3 = tanhf(aw * inv + g4.w);
  ushort4 h4, l4;
  f2hilo(o0, h4.x, l4.x); f2hilo(o1, h4.y, l4.y);
  f2hilo(o2, h4.z, l4.z); f2hilo(o3, h4.w, l4.w);
  *(ushort4*)(xbH + (size_t)j * 256 + lane * 4) = h4;
  *(ushort4*)(xbL + (size_t)j * 256 + lane * 4) = l4;
}

extern "C" void kernel_launch(void* const* d_in, const int* in_sizes, int n_in,
                              void* d_out, int out_size, void* d_ws, size_t ws_size,
                              hipStream_t stream){
  const float* feats   = (const float*)d_in[0];
  const float* Win     = (const float*)d_in[1];
  const float* b_in    = (const float*)d_in[2];
  const float* Wsrc    = (const float*)d_in[3];
  const float* Wdst    = (const float*)d_in[4];
  const float* att_src = (const float*)d_in[5];
  const float* att_dst = (const float*)d_in[6];
  const float* gat_b   = (const float*)d_in[7];
  const float* W_ih    = (const float*)d_in[8];
  const float* W_hh    = (const float*)d_in[9];
  const float* Wout    = (const float*)d_in[10];
  const float* b_out   = (const float*)d_in[11];
  const int* srcs[3] = {(const int*)d_in[12], (const int*)d_in[14], (const int*)d_in[16]};
  const int* dsts[3] = {(const int*)d_in[13], (const int*)d_in[15], (const int*)d_in[17]};
  (void)in_sizes; (void)n_in; (void)out_size; (void)ws_size;

  const int ns_a[3] = {60000, 30000, 15000};
  const int nd_a[3] = {30000, 15000, 7500};
  const int E_a[3]  = {480000, 240000, 120000};

  // ---- workspace layout (~229 MiB), aliasing lifetime-checked ----
  char* w = (char*)d_ws;
  float* xs    = (float*)(w + 0);                 // [60000][256] f32
  u16* featsH  = (u16*)(w + 0);                   // alias: dead before xs written
  u16* featsL  = (u16*)(w + 30720000);
  u16* x0H     = (u16*)(w + 61440000);            // hop-0 x hi/lo
  u16* x0L     = (u16*)(w + 92160000);
  float* c     = (float*)(w + 61440000);          // alias x0H: first write (hop0 epi) after x0 dead
  u16* hAH     = (u16*)(w + 122880000);           // h ping-pong set A
  u16* hAL     = (u16*)(w + 138240000);
  u16* hBH     = (u16*)(w + 153600000);           // set B
  u16* hBL     = (u16*)(w + 168960000);
  u16* xbH     = (u16*)(w + 184320000);
  u16* xbL     = (u16*)(w + 199680000);
  u16* WinH = (u16*)(w + 215040000);  u16* WinL = WinH + 32768;
  u16* WsH  = WinL + 32768;           u16* WsL  = WsH + 196608;
  u16* IhH  = WsL + 196608;           u16* IhL  = IhH + 786432;
  u16* HhH  = IhL + 786432;           u16* HhL  = HhH + 786432;
  u16* WoH  = HhL + 786432;           u16* WoL  = WoH + 32768;
  float* wsv = (float*)(WoL + 32768); float* wdv = wsv + 768;
  float* alpha_s    = wdv + 768;
  float* alpha_d    = alpha_s + 60000;
  float* alpha_e    = alpha_d + 30000;
  float* alpha_self = alpha_e + 480000;
  unsigned* amax    = (unsigned*)(alpha_self + 30000);
  int* cnt          = (int*)(amax + 30000);
  int* base         = cnt + 30000;
  int* cursor       = base + 30000;
  int* part         = cursor + 30000;             // scan partials (<=128)
  int* csr_src      = part + 256;
  float* csr_e      = (float*)(csr_src + 480000);

  // ---- one-time prep (inputs only) ----
  prep_w<<<7168, 256, 0, stream>>>(Win, Wsrc, W_ih, W_hh, Wout,
      WinH, WinL, WsH, WsL, IhH, IhL, HhH, HhL, WoH, WoL);
  prep_wvec<<<384, 256, 0, stream>>>(Wsrc, Wdst, att_src, att_dst, wsv, wdv);
  cvt_feats<<<7500, 256, 0, stream>>>(feats, featsH, featsL, 1920000);

  // ---- input projection: x0(hi/lo) = feats @ Win + b_in ----
  {
    dim3 g(1, CDIV(60000, 256));
    mfma_gemm256<<<g, 512, 0, stream>>>(featsH, featsL, WinH, WinL,
        nullptr, nullptr, nullptr, nullptr, 1, 60000, 256, 128,
        b_in, nullptr, x0H, x0L, nullptr, nullptr, nullptr, nullptr, 0);
  }

  const u16* xHp = x0H; const u16* xLp = x0L;
  u16* hCurH = hAH; u16* hCurL = hAL;   // h produced by previous hop (input to pair1)
  u16* hNewH = hAH; u16* hNewL = hAL;   // h written this hop
  for (int hop = 0; hop < 3; hop++){
    const int ns = ns_a[hop], nd = nd_a[hop], E = E_a[hop];
    const int nb = CDIV(nd, 256);
    hipMemsetAsync(amax, 0, (size_t)(30000 + nd) * 4, stream);  // amax[30000] + cnt[0..nd)

    // xs = x @ Wsrc[hop]   (f32 out, feeds gather)
    {
      dim3 g(1, CDIV(ns, 256));
      mfma_gemm256<<<g, 512, 0, stream>>>(xHp, xLp, WsH + (size_t)hop * 65536, WsL + (size_t)hop * 65536,
          nullptr, nullptr, nullptr, nullptr, 1, ns, 256, 256,
          nullptr, xs, nullptr, nullptr, nullptr, nullptr, nullptr, nullptr, 0);
    }
    alpha_mv<<<CDIV(ns + nd, 4), 256, 0, stream>>>(xHp, xLp, wsv + hop * 256, wdv + hop * 256,
        alpha_s, alpha_d, ns, nd);
    edge_a<<<CDIV(E + nd, 256), 256, 0, stream>>>(srcs[hop], dsts[hop], alpha_s, alpha_d,
        alpha_e, alpha_self, amax, cnt, E, nd);
    scan_part<<<nb, 256, 0, stream>>>(cnt, part, nd);
    scan_fin<<<nb, 256, 0, stream>>>(cnt, part, base, cursor, nd, nb);
    edge_b<<<CDIV(E, 256), 256, 0, stream>>>(srcs[hop], dsts[hop], alpha_e, amax,
        cursor, csr_src, csr_e, E);
    gather_xb<<<CDIV(nd, 4), 256, 0, stream>>>(xs, base, cnt, csr_src, csr_e,
        alpha_self, amax, gat_b + hop * 256, xbH, xbL, nd);

    // gates GEMM with fused LSTM epilogue; h double-buffered (epilogue write vs pair1 read)
    hNewH = (hop == 0) ? hAH : (hCurH == hAH ? hBH : hAH);
    hNewL = (hop == 0) ? hAL : (hCurL == hAL ? hBL : hAL);
    {
      dim3 g(4, CDIV(nd, 256));
      mfma_gemm256<<<g, 512, 0, stream>>>(xbH, xbL, IhH + (size_t)hop * 262144, IhL + (size_t)hop * 262144,
          hCurH, hCurL, HhH + (size_t)hop * 262144, HhL + (size_t)hop * 262144,
          hop ? 2 : 1, nd, 1024, 256,
          nullptr, nullptr, nullptr, nullptr,
          c, c, hNewH, hNewL, hop == 0 ? 1 : 0);
    }
    hCurH = hNewH; hCurL = hNewL;
    xHp = hNewH; xLp = hNewL;
  }

  // ---- output projection (N=128): 128-tile kernel ----
  {
    dim3 g(1, CDIV(7500, 128));
    mfma_gemm<<<g, 256, 0, stream>>>(hCurH, hCurL, WoH, WoL,
        7500, 128, 256, b_out, (float*)d_out);
  }
}

// Round 8
// 653.803 us; speedup vs baseline: 1.2415x; 1.2415x over previous
//
#include <hip/hip_runtime.h>
#include <cstddef>
#include <cstdint>

#define CDIV(a,b) (((a)+(b)-1)/(b))
#define PAD8(x) ((((x)+7)/8)*8)
#define NEG_SLOPE 0.2f

typedef unsigned short u16;
typedef __attribute__((ext_vector_type(8))) short bf16x8;
typedef __attribute__((ext_vector_type(4))) float f32x4;

// ---------- bf16 helpers (explicit RNE, hi/lo split: v ~= hi + lo, ~17 mantissa bits) ----------
__device__ __forceinline__ u16 bf16_rne(float v){
  unsigned u = __float_as_uint(v);
  unsigned r = (u + 0x7FFFu + ((u >> 16) & 1u)) >> 16;
  return (u16)r;
}
__device__ __forceinline__ float bf16_to_f(u16 h){
  return __uint_as_float(((unsigned)h) << 16);
}
__device__ __forceinline__ void f2hilo(float v, u16& h, u16& l){
  h = bf16_rne(v);
  float r = v - bf16_to_f(h);
  l = bf16_rne(r);
}

// ---------- tile-packed operand layout --------------------------------------------
// Matrix [rows][K] stored as bricks: 128-row block r0, k-tile t (BK=32) -> contiguous
// 4096 u16 (8KB). Within a brick, element (rr, k) sits at phys chunk (s+(rr>>1))&3
// (s = (k&31)>>3) -- the LDS bank swizzle is PRE-BAKED, so GEMM staging is a pure
// linear 8KB copy (1KB contiguous per gload16 wave-instruction = ideal DRAM bursts;
// fixes the 64B-stride-512B staging pattern that capped rounds 2-7 at ~0.9-1.7 TB/s).
__device__ __forceinline__ size_t pk_off(int row, int k, int nbk){
  int r0 = row >> 7, rr = row & 127;
  int t = k >> 5, kk = k & 31;
  int s = kk >> 3, w = kk & 7;
  int phys = (s + (rr >> 1)) & 3;
  return ((size_t)(r0 * nbk + t) * 128 + rr) * 32 + phys * 8 + w;
}

// ---------- monotonic float<->uint encoding for atomicMax on floats ----------
__device__ __forceinline__ unsigned enc_f(float x){
  unsigned u = __float_as_uint(x);
  return (u & 0x80000000u) ? ~u : (u | 0x80000000u);
}
__device__ __forceinline__ float dec_f(unsigned k){
  unsigned u = (k & 0x80000000u) ? (k & 0x7FFFFFFFu) : ~k;
  return __uint_as_float(u);
}

__device__ __forceinline__ float sigmf(float x){ return 1.f / (1.f + expf(-x)); }

// ---------- async global->LDS, 16B per lane ----------
__device__ __forceinline__ void gload16(const void* g, void* l){
  __builtin_amdgcn_global_load_lds((const __attribute__((address_space(1))) void*)g,
                                   (__attribute__((address_space(3))) void*)l, 16, 0, 0);
}

// =====================================================================================
// Fused hi/lo MFMA GEMM (round-6 structure + packed operands):
//   C[M,N] = sum_pairs (A_hi+A_lo)(B_hi+B_lo)^T, dropping lo*lo.
// 128x128 tile, 4 waves, BK=32, double-buffered LDS (64KB -> 2 blocks/CU), counted
// vmcnt(8) prefetch. All operands tile-packed (see pk_off): stage = linear 8KB copies.
// Grid = (m-blocks padded %8, n-blocks): column-siblings of an M-block share an XCD
// (bid%8 == bx%8) so A bricks are fetched ~once per XCD L2.
// Epilogues: (a) f32 C (+bias), (b) packed hi/lo bf16, (c) fused LSTM (gate-interleaved
// B: lane's 4 n-frags are i,f,g,o of ONE channel; writes c f32 + packed h hi/lo).
// =====================================================================================
__global__ __launch_bounds__(256, 2) void mfma_gemm(
    const u16* __restrict__ Ah0, const u16* __restrict__ Al0,
    const u16* __restrict__ Bh0, const u16* __restrict__ Bl0,
    const u16* __restrict__ Ah1, const u16* __restrict__ Al1,
    const u16* __restrict__ Bh1, const u16* __restrict__ Bl1,
    int npairs, int M, int N, int K,
    const float* __restrict__ bias, float* __restrict__ Cf,
    u16* __restrict__ outHi, u16* __restrict__ outLo,
    const float* __restrict__ cIn, float* __restrict__ cOut,
    u16* __restrict__ hH, u16* __restrict__ hL, int lstm_first)
{
  if ((int)(blockIdx.x * 128) >= M) return;   // pad-%8 guard (block-uniform)
  __shared__ u16 smem[2 * 16384];  // per buf: Ah@0 Al@4096 Bh@8192 Bl@12288 (u16 units)
  const int tid = threadIdx.x;
  const int lane = tid & 63, wv = tid >> 6;
  const int l15 = lane & 15, lq = lane >> 4;
  const int wr = wv >> 1, wc = wv & 1;
  const int bm = blockIdx.x * 128, bn = blockIdx.y * 128;
  const int nbk = K >> 5, NT = npairs * nbk;
  const size_t Abase = (size_t)(bm >> 7) * nbk * 4096;
  const size_t Bbase = (size_t)(bn >> 7) * nbk * 4096;

  f32x4 acc[4][4];
  #pragma unroll
  for (int m = 0; m < 4; m++)
    #pragma unroll
    for (int n = 0; n < 4; n++) acc[m][n] = (f32x4){0.f, 0.f, 0.f, 0.f};

  // staging: thread's chunk c = i*256+tid -> linear 16B at brick offset c*16
  size_t goff[2]; int ldso2[2];
  #pragma unroll
  for (int i = 0; i < 2; i++){
    goff[i]  = (size_t)(i * 256 + tid) * 8;        // u16 units, contiguous
    ldso2[i] = (i * 256 + (tid & 192)) * 8;        // wave-uniform LDS base
  }

  // fragment read offsets (u16 units within a buffer); phys chunk = (lq + (r>>1)) & 3
  int aoff[4], boff[4];
  #pragma unroll
  for (int m = 0; m < 4; m++){
    int r = wr * 64 + m * 16 + l15;
    aoff[m] = r * 32 + ((lq + (r >> 1)) & 3) * 8;
  }
  #pragma unroll
  for (int n = 0; n < 4; n++){
    int r = wc * 64 + n * 16 + l15;
    boff[n] = r * 32 + ((lq + (r >> 1)) & 3) * 8;
  }

  auto stage = [&](int buf, int t){
    int q = (npairs > 1 && t >= nbk) ? 1 : 0;
    const u16* A_h = q ? Ah1 : Ah0;  const u16* A_l = q ? Al1 : Al0;
    const u16* B_h = q ? Bh1 : Bh0;  const u16* B_l = q ? Bl1 : Bl0;
    int tl = q ? t - nbk : t;
    size_t ab = Abase + (size_t)tl * 4096;
    size_t bb = Bbase + (size_t)tl * 4096;
    u16* sb = smem + buf * 16384;
    #pragma unroll
    for (int i = 0; i < 2; i++){
      gload16(A_h + ab + goff[i], sb + ldso2[i]);
      gload16(A_l + ab + goff[i], sb + 4096 + ldso2[i]);
      gload16(B_h + bb + goff[i], sb + 8192 + ldso2[i]);
      gload16(B_l + bb + goff[i], sb + 12288 + ldso2[i]);
    }
  };

  stage(0, 0);                  // 8 loads/wave outstanding
  int cur = 0;
  #pragma unroll 1
  for (int t = 0; t < NT; t++){
    if (t + 1 < NT){
      stage(cur ^ 1, t + 1);    // +8 -> up to 16 outstanding
      asm volatile("s_waitcnt vmcnt(8)" ::: "memory");   // tile-t landed; t+1 in flight
    } else {
      asm volatile("s_waitcnt vmcnt(0)" ::: "memory");
    }
    __builtin_amdgcn_sched_barrier(0);
    __builtin_amdgcn_s_barrier();        // tile-t visible to all waves
    __builtin_amdgcn_sched_barrier(0);
    const u16* sb = smem + cur * 16384;
    bf16x8 ah[4], al[4], bh[4], bl[4];
    #pragma unroll
    for (int m = 0; m < 4; m++){
      ah[m] = *(const bf16x8*)(sb + aoff[m]);
      al[m] = *(const bf16x8*)(sb + 4096 + aoff[m]);
    }
    #pragma unroll
    for (int n = 0; n < 4; n++){
      bh[n] = *(const bf16x8*)(sb + 8192 + boff[n]);
      bl[n] = *(const bf16x8*)(sb + 12288 + boff[n]);
    }
    #pragma unroll
    for (int m = 0; m < 4; m++)
      #pragma unroll
      for (int n = 0; n < 4; n++){
        acc[m][n] = __builtin_amdgcn_mfma_f32_16x16x32_bf16(ah[m], bh[n], acc[m][n], 0, 0, 0);
        acc[m][n] = __builtin_amdgcn_mfma_f32_16x16x32_bf16(al[m], bh[n], acc[m][n], 0, 0, 0);
        acc[m][n] = __builtin_amdgcn_mfma_f32_16x16x32_bf16(ah[m], bl[n], acc[m][n], 0, 0, 0);
      }
    __builtin_amdgcn_sched_barrier(0);
    __builtin_amdgcn_s_barrier();        // buf[cur] released; NO vmcnt drain
    cur ^= 1;
  }

  // epilogue: C/D layout col=lane&15, row=(lane>>4)*4+j (m89/m91-verified)
  const int rb = bm + wr * 64 + lq * 4;
  if (cOut){
    // LSTM mode: lane owns channel ch; n-frag index == gate (i,f,g,o)
    const int ch = (bn >> 2) + wc * 16 + l15;
    #pragma unroll
    for (int m = 0; m < 4; m++){
      #pragma unroll
      for (int j = 0; j < 4; j++){
        int row = rb + m * 16 + j;
        if (row >= M) continue;
        float i_ = acc[m][0][j], f_ = acc[m][1][j], g_ = acc[m][2][j], o_ = acc[m][3][j];
        float si = sigmf(i_), tg = tanhf(g_), so = sigmf(o_);
        size_t loff = (size_t)row * 256 + ch;
        float cn = lstm_first ? si * tg : sigmf(f_) * cIn[loff] + si * tg;
        float hn = so * tanhf(cn);
        cOut[loff] = cn;
        u16 hh, hl; f2hilo(hn, hh, hl);
        size_t pko = pk_off(row, ch, 8);
        hH[pko] = hh; hL[pko] = hl;
      }
    }
  } else {
    const int cb = bn + wc * 64 + l15;
    #pragma unroll
    for (int n = 0; n < 4; n++){
      int col = cb + n * 16;
      float bv = bias ? bias[col] : 0.f;
      #pragma unroll
      for (int m = 0; m < 4; m++){
        #pragma unroll
        for (int j = 0; j < 4; j++){
          int row = rb + m * 16 + j;
          if (row >= M) continue;
          float v = acc[m][n][j] + bv;
          if (Cf) Cf[(size_t)row * N + col] = v;
          if (outHi){
            u16 hh, hl; f2hilo(v, hh, hl);
            size_t pko = pk_off(row, col, 8);
            outHi[pko] = hh; outLo[pko] = hl;
          }
        }
      }
    }
  }
}

// ---------- feats f32 [60000][128] -> packed hi/lo bf16 (nbk=4), 4 elems/thread ----------
__global__ __launch_bounds__(256) void cvt_feats(const float* __restrict__ in,
    u16* __restrict__ hi, u16* __restrict__ lo, int nrow){
  int i = blockIdx.x * 256 + threadIdx.x;       // quad index
  int row = i >> 5, k4 = (i & 31) * 4;
  if (row >= nrow) return;
  float4 v = *(const float4*)(in + (size_t)row * 128 + k4);
  ushort4 h4, l4;
  f2hilo(v.x, h4.x, l4.x); f2hilo(v.y, h4.y, l4.y);
  f2hilo(v.z, h4.z, l4.z); f2hilo(v.w, h4.w, l4.w);
  size_t off = pk_off(row, k4, 4);              // w in {0,4}: ushort4 stays in-chunk
  *(ushort4*)(hi + off) = h4;
  *(ushort4*)(lo + off) = l4;
}

// ---------- one-shot weight prep: transpose/permute + PACKED hi/lo bf16 ----------
// W_ih/W_hh rows PERMUTED to gate-interleaved layout: orig row (gate*256+ch)
// -> n' = (ch>>4)*64 + gate*16 + (ch&15), so the GEMM epilogue can fuse LSTM.
__global__ __launch_bounds__(256) void prep_w(const float* __restrict__ Win,
    const float* __restrict__ Wsrc, const float* __restrict__ Wih,
    const float* __restrict__ Whh, const float* __restrict__ Wout,
    u16* WinH, u16* WinL, u16* WsH, u16* WsL,
    u16* IhH, u16* IhL, u16* HhH, u16* HhL, u16* WoH, u16* WoL){
  int idx = blockIdx.x * 256 + threadIdx.x;
  float v; u16 *ph, *pl; size_t off;
  if (idx < 32768){                       // WinT [256][128] <- Win[128][256]; nbk=4
    int n = idx >> 7, k = idx & 127;
    v = Win[k * 256 + n]; ph = WinH; pl = WinL; off = pk_off(n, k, 4);
  } else if (idx < 229376){               // WsT [3][256][256] <- Wsrc^T; nbk=8
    int t = idx - 32768; int hop = t >> 16, r = t & 65535, n = r >> 8, k = r & 255;
    v = Wsrc[hop * 65536 + k * 256 + n]; ph = WsH; pl = WsL;
    off = (size_t)hop * 65536 + pk_off(n, k, 8);
  } else if (idx < 1015808){              // W_ih [3][1024][256], gate-interleaved; nbk=8
    int t = idx - 229376;
    int hop = t >> 18, r = (t >> 8) & 1023, k = t & 255;
    int gate = r >> 8, ch = r & 255;
    int np = ((ch >> 4) << 6) + (gate << 4) + (ch & 15);
    v = Wih[t]; ph = IhH; pl = IhL;
    off = (size_t)hop * 262144 + pk_off(np, k, 8);
  } else if (idx < 1802240){              // W_hh, same permutation
    int t = idx - 1015808;
    int hop = t >> 18, r = (t >> 8) & 1023, k = t & 255;
    int gate = r >> 8, ch = r & 255;
    int np = ((ch >> 4) << 6) + (gate << 4) + (ch & 15);
    v = Whh[t]; ph = HhH; pl = HhL;
    off = (size_t)hop * 262144 + pk_off(np, k, 8);
  } else if (idx < 1835008){              // WoT [128][256] <- Wout^T; nbk=8
    int t = idx - 1802240; int n = t >> 8, k = t & 255;
    v = Wout[k * 128 + n]; ph = WoH; pl = WoL; off = pk_off(n, k, 8);
  } else return;
  u16 hh, hl; f2hilo(v, hh, hl);
  ph[off] = hh; pl[off] = hl;
}

// ---------- w_s[hop] = Wsrc[hop]@a_s, w_d[hop] = Wdst[hop]@a_d (row dots, f32) ----------
__global__ __launch_bounds__(256) void prep_wvec(const float* __restrict__ Wsrc,
    const float* __restrict__ Wdst, const float* __restrict__ as_,
    const float* __restrict__ ad_, float* __restrict__ wsv, float* __restrict__ wdv){
  int wid = blockIdx.x * 4 + (threadIdx.x >> 6), lane = threadIdx.x & 63;
  if (wid >= 6 * 256) return;
  int vec = wid >> 8, i = wid & 255;
  int hop = vec >> 1; bool isd = vec & 1;
  const float* Wrow = (isd ? Wdst : Wsrc) + (size_t)hop * 65536 + (size_t)i * 256;
  const float* a = (isd ? ad_ : as_) + hop * 256;
  float4 w4 = *(const float4*)(Wrow + lane * 4);
  float4 a4 = *(const float4*)(a + lane * 4);
  float v = w4.x * a4.x + w4.y * a4.y + w4.z * a4.z + w4.w * a4.w;
  #pragma unroll
  for (int off = 32; off; off >>= 1) v += __shfl_down(v, off);
  if (!lane) (isd ? wdv : wsv)[hop * 256 + i] = v;
}

// ---------- alpha_s[m]=x[m]@w_s, alpha_d[m]=x[m]@w_d from PACKED hi/lo x ----------
__global__ __launch_bounds__(256) void alpha_mv(const u16* __restrict__ xh,
    const u16* __restrict__ xl, const float* __restrict__ wsv, const float* __restrict__ wdv,
    float* __restrict__ as_out, float* __restrict__ ad_out, int ns, int nd){
  int wid = blockIdx.x * 4 + (threadIdx.x >> 6), lane = threadIdx.x & 63;
  if (wid >= ns + nd) return;
  bool isd = wid >= ns;
  int row = isd ? wid - ns : wid;
  size_t off = pk_off(row, lane * 4, 8);
  ushort4 vh = *(const ushort4*)(xh + off);
  ushort4 vl = *(const ushort4*)(xl + off);
  const float* wv = isd ? wdv : wsv;
  float4 w4 = *(const float4*)(wv + lane * 4);
  float v = (bf16_to_f(vh.x) + bf16_to_f(vl.x)) * w4.x
          + (bf16_to_f(vh.y) + bf16_to_f(vl.y)) * w4.y
          + (bf16_to_f(vh.z) + bf16_to_f(vl.z)) * w4.z
          + (bf16_to_f(vh.w) + bf16_to_f(vl.w)) * w4.w;
  #pragma unroll
  for (int off2 = 32; off2; off2 >>= 1) v += __shfl_down(v, off2);
  if (!lane) (isd ? ad_out : as_out)[row] = v;
}

// ---------- edges + self-loops: leaky-relu alpha, segment max (encoded), degree ----------
__global__ __launch_bounds__(256) void edge_a(const int* __restrict__ src,
    const int* __restrict__ dst, const float* __restrict__ as_, const float* __restrict__ ad_,
    float* __restrict__ alpha_e, float* __restrict__ alpha_self,
    unsigned* __restrict__ amax, int* __restrict__ cnt, int E, int nd){
  int i = blockIdx.x * 256 + threadIdx.x;
  if (i < E){
    int s = src[i], d = dst[i];
    float al = as_[s] + ad_[d];
    al = al > 0.f ? al : NEG_SLOPE * al;
    alpha_e[i] = al;
    atomicMax(&amax[d], enc_f(al));
    atomicAdd(&cnt[d], 1);
  } else if (i < E + nd){
    int j = i - E;
    float al = as_[j] + ad_[j];
    al = al > 0.f ? al : NEG_SLOPE * al;
    alpha_self[j] = al;
    atomicMax(&amax[j], enc_f(al));
  }
}

// ---------- scan, 2 dispatches ----------
__global__ __launch_bounds__(256) void scan_part(const int* __restrict__ cnt,
    int* __restrict__ part, int n){
  __shared__ int ws_[4];
  int lane = threadIdx.x & 63, wv = threadIdx.x >> 6;
  int i = blockIdx.x * 256 + threadIdx.x;
  int v = (i < n) ? cnt[i] : 0;
  #pragma unroll
  for (int off = 32; off; off >>= 1) v += __shfl_down(v, off);
  if (!lane) ws_[wv] = v;
  __syncthreads();
  if (!threadIdx.x) part[blockIdx.x] = ws_[0] + ws_[1] + ws_[2] + ws_[3];
}
__global__ __launch_bounds__(256) void scan_fin(const int* __restrict__ cnt,
    const int* __restrict__ part, int* __restrict__ base, int* __restrict__ cursor,
    int n, int nb){
  __shared__ int ps[128];
  __shared__ int wtot[4];
  int t = threadIdx.x;
  if (t < 128) ps[t] = (t < nb) ? part[t] : 0;
  __syncthreads();
  #pragma unroll
  for (int off = 1; off < 128; off <<= 1){
    int v = (t < 128 && t >= off) ? ps[t - off] : 0;
    __syncthreads();
    if (t < 128) ps[t] += v;
    __syncthreads();
  }
  int lane = t & 63, wv = t >> 6;
  int i = blockIdx.x * 256 + t;
  int v = (i < n) ? cnt[i] : 0;
  int incl = v;
  #pragma unroll
  for (int off = 1; off < 64; off <<= 1){
    int s = __shfl_up(incl, off);
    if (lane >= off) incl += s;
  }
  if (lane == 63) wtot[wv] = incl;
  __syncthreads();
  int woff = blockIdx.x ? ps[blockIdx.x - 1] : 0;
  for (int w = 0; w < wv; w++) woff += wtot[w];
  int excl = woff + incl - v;
  if (i < n){ base[i] = excl; cursor[i] = excl; }
}

// ---------- e=exp(alpha-amax), CSR fill ----------
__global__ __launch_bounds__(256) void edge_b(const int* __restrict__ src,
    const int* __restrict__ dst, const float* __restrict__ alpha_e,
    const unsigned* __restrict__ amax, int* __restrict__ cursor,
    int* __restrict__ csr_src, float* __restrict__ csr_e, int E){
  int e = blockIdx.x * 256 + threadIdx.x;
  if (e >= E) return;
  int d = dst[e];
  float ev = expf(alpha_e[e] - dec_f(amax[d]));
  int pos = atomicAdd(&cursor[d], 1);
  csr_src[pos] = src[e];
  csr_e[pos] = ev;
}

// ---------- gather + normalize + bias + tanh -> PACKED xb hi/lo; one wave/dst ----------
__global__ __launch_bounds__(256) void gather_xb(const float* __restrict__ xs,
    const int* __restrict__ base, const int* __restrict__ cnt,
    const int* __restrict__ csr_src, const float* __restrict__ csr_e,
    const float* __restrict__ alpha_self, const unsigned* __restrict__ amax,
    const float* __restrict__ gb, u16* __restrict__ xbH, u16* __restrict__ xbL, int n){
  int wv = threadIdx.x >> 6, lane = threadIdx.x & 63;
  int j = blockIdx.x * 4 + wv;
  if (j >= n) return;
  int b0 = base[j], cn = cnt[j];
  float ax = 0.f, ay = 0.f, az = 0.f, aw = 0.f, ds = 0.f;
  for (int k = 0; k < cn; k++){
    int s = csr_src[b0 + k];
    float ev = csr_e[b0 + k];
    float4 x4 = *(const float4*)(xs + (size_t)s * 256 + lane * 4);
    ax += ev * x4.x; ay += ev * x4.y; az += ev * x4.z; aw += ev * x4.w; ds += ev;
  }
  float es = expf(alpha_self[j] - dec_f(amax[j]));
  float4 x4 = *(const float4*)(xs + (size_t)j * 256 + lane * 4);
  ax += es * x4.x; ay += es * x4.y; az += es * x4.z; aw += es * x4.w; ds += es;
  float inv = 1.f / ds;
  float4 g4 = *(const float4*)(gb + lane * 4);
  float o0 = tanhf(ax * inv + g4.x), o1 = tanhf(ay * inv + g4.y);
  float o2 = tanhf(az * inv + g4.z), o3 = tanhf(aw * inv + g4.w);
  ushort4 h4, l4;
  f2hilo(o0, h4.x, l4.x); f2hilo(o1, h4.y, l4.y);
  f2hilo(o2, h4.z, l4.z); f2hilo(o3, h4.w, l4.w);
  size_t off = pk_off(j, lane * 4, 8);
  *(ushort4*)(xbH + off) = h4;
  *(ushort4*)(xbL + off) = l4;
}

extern "C" void kernel_launch(void* const* d_in, const int* in_sizes, int n_in,
                              void* d_out, int out_size, void* d_ws, size_t ws_size,
                              hipStream_t stream){
  const float* feats   = (const float*)d_in[0];
  const float* Win     = (const float*)d_in[1];
  const float* b_in    = (const float*)d_in[2];
  const float* Wsrc    = (const float*)d_in[3];
  const float* Wdst    = (const float*)d_in[4];
  const float* att_src = (const float*)d_in[5];
  const float* att_dst = (const float*)d_in[6];
  const float* gat_b   = (const float*)d_in[7];
  const float* W_ih    = (const float*)d_in[8];
  const float* W_hh    = (const float*)d_in[9];
  const float* Wout    = (const float*)d_in[10];
  const float* b_out   = (const float*)d_in[11];
  const int* srcs[3] = {(const int*)d_in[12], (const int*)d_in[14], (const int*)d_in[16]};
  const int* dsts[3] = {(const int*)d_in[13], (const int*)d_in[15], (const int*)d_in[17]};
  (void)in_sizes; (void)n_in; (void)out_size; (void)ws_size;

  const int ns_a[3] = {60000, 30000, 15000};
  const int nd_a[3] = {30000, 15000, 7500};
  const int E_a[3]  = {480000, 240000, 120000};

  // ---- workspace layout (~230 MiB), aliasing lifetime-checked ----
  // Packed buffers are padded to 128-row blocks (garbage pad rows only feed
  // discarded C rows).
  char* w = (char*)d_ws;
  float* xs    = (float*)(w + 0);                 // [60000][256] f32 (61.44MB)
  u16* featsH  = (u16*)(w + 0);                   // packed 60032x128 (15.37MB); dead before xs
  u16* featsL  = (u16*)(w + 15400000);
  u16* x0H     = (u16*)(w + 61440000);            // packed 60032x256 (30.74MB)
  u16* x0L     = (u16*)(w + 92200000);
  float* c     = (float*)(w + 61440000);          // [30000][256] f32; alias x0H (x0 dead first)
  u16* hAH     = (u16*)(w + 123000000);           // packed 30080x256 (15.41MB) ping-pong A
  u16* hAL     = (u16*)(w + 138500000);
  u16* hBH     = (u16*)(w + 154000000);           // set B
  u16* hBL     = (u16*)(w + 169500000);
  u16* xbH     = (u16*)(w + 185000000);
  u16* xbL     = (u16*)(w + 200500000);
  u16* WinH = (u16*)(w + 216000000);  u16* WinL = WinH + 32768;
  u16* WsH  = WinL + 32768;           u16* WsL  = WsH + 196608;
  u16* IhH  = WsL + 196608;           u16* IhL  = IhH + 786432;
  u16* HhH  = IhL + 786432;           u16* HhL  = HhH + 786432;
  u16* WoH  = HhL + 786432;           u16* WoL  = WoH + 32768;
  float* wsv = (float*)(w + 223400000); float* wdv = wsv + 768;
  float* alpha_s    = wdv + 768;
  float* alpha_d    = alpha_s + 60000;
  float* alpha_e    = alpha_d + 30000;
  float* alpha_self = alpha_e + 480000;
  unsigned* amax    = (unsigned*)(alpha_self + 30000);
  int* cnt          = (int*)(amax + 30000);
  int* base         = cnt + 30000;
  int* cursor       = base + 30000;
  int* part         = cursor + 30000;             // scan partials (<=128)
  int* csr_src      = part + 256;
  float* csr_e      = (float*)(csr_src + 480000);

  // ---- one-time prep (inputs only) ----
  prep_w<<<7168, 256, 0, stream>>>(Win, Wsrc, W_ih, W_hh, Wout,
      WinH, WinL, WsH, WsL, IhH, IhL, HhH, HhL, WoH, WoL);
  prep_wvec<<<384, 256, 0, stream>>>(Wsrc, Wdst, att_src, att_dst, wsv, wdv);
  cvt_feats<<<7500, 256, 0, stream>>>(feats, featsH, featsL, 60000);

  // ---- input projection: x0(packed hi/lo) = feats @ Win + b_in ----
  {
    dim3 g(PAD8(CDIV(60000, 128)), 2);
    mfma_gemm<<<g, 256, 0, stream>>>(featsH, featsL, WinH, WinL,
        nullptr, nullptr, nullptr, nullptr, 1, 60000, 256, 128,
        b_in, nullptr, x0H, x0L, nullptr, nullptr, nullptr, nullptr, 0);
  }

  const u16* xHp = x0H; const u16* xLp = x0L;
  u16* hCurH = hAH; u16* hCurL = hAL;   // h produced by previous hop (input to pair1)
  for (int hop = 0; hop < 3; hop++){
    const int ns = ns_a[hop], nd = nd_a[hop], E = E_a[hop];
    const int nb = CDIV(nd, 256);
    hipMemsetAsync(amax, 0, (size_t)(30000 + nd) * 4, stream);  // amax[30000] + cnt[0..nd)

    // xs = x @ Wsrc[hop]   (f32 out, feeds gather)
    {
      dim3 g(PAD8(CDIV(ns, 128)), 2);
      mfma_gemm<<<g, 256, 0, stream>>>(xHp, xLp, WsH + (size_t)hop * 65536, WsL + (size_t)hop * 65536,
          nullptr, nullptr, nullptr, nullptr, 1, ns, 256, 256,
          nullptr, xs, nullptr, nullptr, nullptr, nullptr, nullptr, nullptr, 0);
    }
    alpha_mv<<<CDIV(ns + nd, 4), 256, 0, stream>>>(xHp, xLp, wsv + hop * 256, wdv + hop * 256,
        alpha_s, alpha_d, ns, nd);
    edge_a<<<CDIV(E + nd, 256), 256, 0, stream>>>(srcs[hop], dsts[hop], alpha_s, alpha_d,
        alpha_e, alpha_self, amax, cnt, E, nd);
    scan_part<<<nb, 256, 0, stream>>>(cnt, part, nd);
    scan_fin<<<nb, 256, 0, stream>>>(cnt, part, base, cursor, nd, nb);
    edge_b<<<CDIV(E, 256), 256, 0, stream>>>(srcs[hop], dsts[hop], alpha_e, amax,
        cursor, csr_src, csr_e, E);
    gather_xb<<<CDIV(nd, 4), 256, 0, stream>>>(xs, base, cnt, csr_src, csr_e,
        alpha_self, amax, gat_b + hop * 256, xbH, xbL, nd);

    // gates GEMM with fused LSTM epilogue; h double-buffered (epilogue write vs pair1 read)
    u16* hNewH = (hop == 0) ? hAH : (hCurH == hAH ? hBH : hAH);
    u16* hNewL = (hop == 0) ? hAL : (hCurL == hAL ? hBL : hAL);
    {
      dim3 g(PAD8(CDIV(nd, 128)), 8);
      mfma_gemm<<<g, 256, 0, stream>>>(xbH, xbL, IhH + (size_t)hop * 262144, IhL + (size_t)hop * 262144,
          hCurH, hCurL, HhH + (size_t)hop * 262144, HhL + (size_t)hop * 262144,
          hop ? 2 : 1, nd, 1024, 256,
          nullptr, nullptr, nullptr, nullptr,
          c, c, hNewH, hNewL, hop == 0 ? 1 : 0);
    }
    hCurH = hNewH; hCurL = hNewL;
    xHp = hNewH; xLp = hNewL;
  }

  // ---- output projection (N=128): d_out = h @ Wout + b_out ----
  {
    dim3 g(PAD8(CDIV(7500, 128)), 1);
    mfma_gemm<<<g, 256, 0, stream>>>(hCurH, hCurL, WoH, WoL,
        nullptr, nullptr, nullptr, nullptr, 1, 7500, 128, 256,
        b_out, (float*)d_out, nullptr, nullptr, nullptr, nullptr, nullptr, nullptr, 0);
  }
}